// Round 1
// baseline (15964.482 us; speedup 1.0000x reference)
//
#include <hip/hip_runtime.h>
#include <math.h>

#define HID 256
#define TSTEPS 256
#define ROWS 2

// One block per 2 batch rows; 512 threads = (K-half 0/1) x (gate column j 0..255).
// Each thread streams 4 W_hh rows (its gate column for i,f,g,o) over its K-half,
// reusing each W element for both batch rows (register reuse). h lives in LDS.
__global__ __launch_bounds__(512) void decoder_kernel(
    const float* __restrict__ enc,   // (512, 64, 256)
    const float* __restrict__ b_ih,  // (1024)
    const float* __restrict__ W_hh,  // (1024, 256)
    const float* __restrict__ b_hh,  // (1024)
    const float* __restrict__ W2,    // (256, 256)
    const float* __restrict__ b2,    // (256)
    float* __restrict__ out)         // (512, 256, 256)
{
    const int tid  = threadIdx.x;
    const int j    = tid & 255;
    const int half = tid >> 8;       // K-half: 0 or 1
    const int b0   = blockIdx.x * ROWS;
    const int k0   = half * 128;

    __shared__ float h_lds[ROWS][HID];
    __shared__ float hn_lds[ROWS][HID];
    __shared__ float part[256][4][ROWS];   // gate partials from half 1
    __shared__ float part2[256][ROWS];     // logit partials from half 1
    __shared__ float logit_lds[ROWS][HID];
    __shared__ float red_m[ROWS][4];
    __shared__ float red_s[ROWS][4];

    if (half == 0) {
        h_lds[0][j] = 0.0f;
        h_lds[1][j] = 0.0f;
    }

    float bias0 = 0.f, bias1 = 0.f, bias2v = 0.f, bias3 = 0.f;
    float c00 = 0.f, c01 = 0.f;
    if (half == 0) {
        bias0  = b_ih[j      ] + b_hh[j      ];
        bias1  = b_ih[j + 256] + b_hh[j + 256];
        bias2v = b_ih[j + 512] + b_hh[j + 512];
        bias3  = b_ih[j + 768] + b_hh[j + 768];
        // c0 = encoder_output[:, 63, :]
        c00 = enc[(size_t)(b0    ) * 16384 + 16128 + j];
        c01 = enc[(size_t)(b0 + 1) * 16384 + 16128 + j];
    }
    const float bb2 = b2[j];

    const float4* __restrict__ Wp0 = (const float4*)(W_hh + (size_t)(j      ) * HID + k0);
    const float4* __restrict__ Wp1 = (const float4*)(W_hh + (size_t)(j + 256) * HID + k0);
    const float4* __restrict__ Wp2 = (const float4*)(W_hh + (size_t)(j + 512) * HID + k0);
    const float4* __restrict__ Wp3 = (const float4*)(W_hh + (size_t)(j + 768) * HID + k0);
    const float4* __restrict__ Wo  = (const float4*)(W2   + (size_t)j * HID + k0);

    float* __restrict__ out0 = out + (size_t)b0 * TSTEPS * 256 + j;
    float* __restrict__ out1 = out0 + (size_t)TSTEPS * 256;
    float* __restrict__ outh = half ? out1 : out0;

    __syncthreads();

    for (int t = 0; t < TSTEPS; ++t) {
        // ---- phase 1: gate GEMM partials over this thread's K-half ----
        float a00=0.f,a01=0.f,a10=0.f,a11=0.f,a20=0.f,a21=0.f,a30=0.f,a31=0.f;
        #pragma unroll 4
        for (int kk = 0; kk < 32; ++kk) {
            const float4 h0 = *(const float4*)&h_lds[0][k0 + kk*4];
            const float4 h1 = *(const float4*)&h_lds[1][k0 + kk*4];
            float4 w;
            w = Wp0[kk];
            a00 += w.x*h0.x + w.y*h0.y + w.z*h0.z + w.w*h0.w;
            a01 += w.x*h1.x + w.y*h1.y + w.z*h1.z + w.w*h1.w;
            w = Wp1[kk];
            a10 += w.x*h0.x + w.y*h0.y + w.z*h0.z + w.w*h0.w;
            a11 += w.x*h1.x + w.y*h1.y + w.z*h1.z + w.w*h1.w;
            w = Wp2[kk];
            a20 += w.x*h0.x + w.y*h0.y + w.z*h0.z + w.w*h0.w;
            a21 += w.x*h1.x + w.y*h1.y + w.z*h1.z + w.w*h1.w;
            w = Wp3[kk];
            a30 += w.x*h0.x + w.y*h0.y + w.z*h0.z + w.w*h0.w;
            a31 += w.x*h1.x + w.y*h1.y + w.z*h1.z + w.w*h1.w;
        }
        if (half == 1) {
            part[j][0][0]=a00; part[j][0][1]=a01;
            part[j][1][0]=a10; part[j][1][1]=a11;
            part[j][2][0]=a20; part[j][2][1]=a21;
            part[j][3][0]=a30; part[j][3][1]=a31;
        }
        __syncthreads();   // (1) partials visible; all h reads done

        if (half == 0) {
            {
                float gi = a00 + part[j][0][0] + bias0;
                float gf = a10 + part[j][1][0] + bias1;
                float gg = a20 + part[j][2][0] + bias2v;
                float go = a30 + part[j][3][0] + bias3;
                float si = 1.0f/(1.0f+expf(-gi));
                float sf = 1.0f/(1.0f+expf(-gf));
                float so = 1.0f/(1.0f+expf(-go));
                float tg = tanhf(gg);
                float c  = sf*c00 + si*tg;
                float hn = so * tanhf(c);
                h_lds[0][j]  = c;    // carry h_{t+1} = c_new (reference semantics)
                hn_lds[0][j] = hn;
            }
            {
                float gi = a01 + part[j][0][1] + bias0;
                float gf = a11 + part[j][1][1] + bias1;
                float gg = a21 + part[j][2][1] + bias2v;
                float go = a31 + part[j][3][1] + bias3;
                float si = 1.0f/(1.0f+expf(-gi));
                float sf = 1.0f/(1.0f+expf(-gf));
                float so = 1.0f/(1.0f+expf(-go));
                float tg = tanhf(gg);
                float c  = sf*c01 + si*tg;
                float hn = so * tanhf(c);
                h_lds[1][j]  = c;
                hn_lds[1][j] = hn;
            }
        }
        __syncthreads();   // (2) h_new ready

        // ---- phase 2: logits ----
        float l0 = 0.f, l1 = 0.f;
        #pragma unroll 4
        for (int kk = 0; kk < 32; ++kk) {
            const float4 w  = Wo[kk];
            const float4 n0 = *(const float4*)&hn_lds[0][k0 + kk*4];
            const float4 n1 = *(const float4*)&hn_lds[1][k0 + kk*4];
            l0 += w.x*n0.x + w.y*n0.y + w.z*n0.z + w.w*n0.w;
            l1 += w.x*n1.x + w.y*n1.y + w.z*n1.z + w.w*n1.w;
        }
        if (half == 1) { part2[j][0] = l0; part2[j][1] = l1; }
        __syncthreads();   // (3)
        if (half == 0) {
            logit_lds[0][j] = l0 + part2[j][0] + bb2;
            logit_lds[1][j] = l1 + part2[j][1] + bb2;
        }
        __syncthreads();   // (4)

        // ---- phase 3: softmax; 256 threads per row (row = half) ----
        const float v = logit_lds[half][j];
        float m = v;
        #pragma unroll
        for (int off = 32; off > 0; off >>= 1)
            m = fmaxf(m, __shfl_xor(m, off));
        const int w4 = (tid >> 6) & 3;
        if ((tid & 63) == 0) red_m[half][w4] = m;
        __syncthreads();   // (5)
        m = fmaxf(fmaxf(red_m[half][0], red_m[half][1]),
                  fmaxf(red_m[half][2], red_m[half][3]));
        const float e = expf(v - m);
        float s = e;
        #pragma unroll
        for (int off = 32; off > 0; off >>= 1)
            s += __shfl_xor(s, off);
        if ((tid & 63) == 0) red_s[half][w4] = s;
        __syncthreads();   // (6)
        s = red_s[half][0] + red_s[half][1] + red_s[half][2] + red_s[half][3];
        outh[t * 256] = e / s;
    }
}

extern "C" void kernel_launch(void* const* d_in, const int* in_sizes, int n_in,
                              void* d_out, int out_size, void* d_ws, size_t ws_size,
                              hipStream_t stream) {
    // setup_inputs order: input, encoder_output, W_ih, b_ih, W_hh, b_hh, W2, b2
    // (input and W_ih are mathematically unused: x_part = 0 @ W_ih.T + b_ih)
    const float* enc  = (const float*)d_in[1];
    const float* b_ih = (const float*)d_in[3];
    const float* W_hh = (const float*)d_in[4];
    const float* b_hh = (const float*)d_in[5];
    const float* W2   = (const float*)d_in[6];
    const float* b2   = (const float*)d_in[7];
    float* outp = (float*)d_out;

    dim3 grid(256), block(512);
    hipLaunchKernelGGL(decoder_kernel, grid, block, 0, stream,
                       enc, b_ih, W_hh, b_hh, W2, b2, outp);
}

// Round 4
// 7900.478 us; speedup vs baseline: 2.0207x; 2.0207x over previous
//
#include <hip/hip_runtime.h>
#include <math.h>

#define HID 256
#define TSTEPS 256

typedef float f32x4 __attribute__((ext_vector_type(4)));

__device__ __forceinline__ float dot4(float4 a, float4 b) {
    return a.x*b.x + a.y*b.y + a.z*b.z + a.w*b.w;
}
__device__ __forceinline__ float sigmoidf_(float x) { return 1.0f/(1.0f+expf(-x)); }

// ---------------- Kernel 1: LSTM recurrence ----------------
// 128 blocks x 1024 threads. Block handles 4 batch rows.
// Thread (j = tid&255, q = tid>>8): gate-column j, K-quarter q (64 K-elems),
// and pointwise/LSTM duties for row q. Weights streamed from L2 (kept
// resident by making the h stores non-temporal). 2 barriers/step.
// NOTE reference semantics: cell_state is CONSTANT (enc[:,-1,:]) every step;
// the scan carry is h_{t+1} = c_new_t. (Round-3 bug: accumulated c.)
__global__ __launch_bounds__(1024) void rec_kernel(
    const float* __restrict__ enc,   // (512, 64, 256)
    const float* __restrict__ b_ih,  // (1024)
    const float* __restrict__ W_hh,  // (1024, 256)
    const float* __restrict__ b_hh,  // (1024)
    float* __restrict__ hstage)      // (512, 256, 256) staging (= d_out)
{
    const int tid = threadIdx.x;
    const int j   = tid & 255;
    const int q   = tid >> 8;        // 0..3
    const int b0  = blockIdx.x * 4;

    __shared__ float h_lds[4][HID];            // carry (= previous c_new) per row
    __shared__ float part[4][4][4][HID];       // [gate][row][quarter][col]

    h_lds[q][j] = 0.0f;

    float bias[4];
    #pragma unroll
    for (int g = 0; g < 4; ++g)
        bias[g] = b_ih[g*256 + j] + b_hh[g*256 + j];

    // constant cell state: encoder_output[:, 63, :]
    const float c0 = enc[(size_t)(b0 + q) * 16384 + 16128 + j];

    const float4* __restrict__ Wg0 = (const float4*)(W_hh + (size_t)(0*256 + j)*256 + q*64);
    const float4* __restrict__ Wg1 = (const float4*)(W_hh + (size_t)(1*256 + j)*256 + q*64);
    const float4* __restrict__ Wg2 = (const float4*)(W_hh + (size_t)(2*256 + j)*256 + q*64);
    const float4* __restrict__ Wg3 = (const float4*)(W_hh + (size_t)(3*256 + j)*256 + q*64);

    float* __restrict__ outp = hstage + (size_t)(b0 + q) * (TSTEPS*256) + j;

    __syncthreads();

    for (int t = 0; t < TSTEPS; ++t) {
        float a00=0.f,a01=0.f,a02=0.f,a03=0.f;
        float a10=0.f,a11=0.f,a12=0.f,a13=0.f;
        float a20=0.f,a21=0.f,a22=0.f,a23=0.f;
        float a30=0.f,a31=0.f,a32=0.f,a33=0.f;

        #pragma unroll 4
        for (int k4 = 0; k4 < 16; ++k4) {
            const float4 h0 = *(const float4*)&h_lds[0][q*64 + k4*4];  // broadcast reads
            const float4 h1 = *(const float4*)&h_lds[1][q*64 + k4*4];
            const float4 h2 = *(const float4*)&h_lds[2][q*64 + k4*4];
            const float4 h3 = *(const float4*)&h_lds[3][q*64 + k4*4];
            float4 w;
            w = Wg0[k4]; a00+=dot4(w,h0); a01+=dot4(w,h1); a02+=dot4(w,h2); a03+=dot4(w,h3);
            w = Wg1[k4]; a10+=dot4(w,h0); a11+=dot4(w,h1); a12+=dot4(w,h2); a13+=dot4(w,h3);
            w = Wg2[k4]; a20+=dot4(w,h0); a21+=dot4(w,h1); a22+=dot4(w,h2); a23+=dot4(w,h3);
            w = Wg3[k4]; a30+=dot4(w,h0); a31+=dot4(w,h1); a32+=dot4(w,h2); a33+=dot4(w,h3);
        }

        // partials: lane-consecutive in j -> conflict-free (2-way max)
        part[0][0][q][j]=a00; part[0][1][q][j]=a01; part[0][2][q][j]=a02; part[0][3][q][j]=a03;
        part[1][0][q][j]=a10; part[1][1][q][j]=a11; part[1][2][q][j]=a12; part[1][3][q][j]=a13;
        part[2][0][q][j]=a20; part[2][1][q][j]=a21; part[2][2][q][j]=a22; part[2][3][q][j]=a23;
        part[3][0][q][j]=a30; part[3][1][q][j]=a31; part[3][2][q][j]=a32; part[3][3][q][j]=a33;
        __syncthreads();   // (1) partials ready; h reads done

        // thread (j,q) does LSTM pointwise for row q, column j
        float gate[4];
        #pragma unroll
        for (int g = 0; g < 4; ++g)
            gate[g] = part[g][q][0][j] + part[g][q][1][j]
                    + part[g][q][2][j] + part[g][q][3][j] + bias[g];

        const float si = sigmoidf_(gate[0]);
        const float sf = sigmoidf_(gate[1]);
        const float tg = tanhf(gate[2]);
        const float so = sigmoidf_(gate[3]);
        const float cn = sf*c0 + si*tg;      // c0 CONSTANT (reference closure)
        const float hn = so * tanhf(cn);

        h_lds[q][j] = cn;   // carry h_{t+1} = c_new (reference semantics)
        __builtin_nontemporal_store(hn, outp + t*256);
        __syncthreads();   // (2) h ready for next step
    }
}

// ---------------- Kernel 2: logits + softmax, in place ----------------
// 2048 blocks x 1024 threads; block does 64 (b,t) rows x 256 cols.
// Thread (rg = tid&15, cg = tid>>4): rows {rg, rg+16, rg+32, rg+48},
// cols {4cg..4cg+3} -> 4x4 register tile. Pad 260: row stride 4 banks
// -> ds_read_b128 is 2-way (free). Wave-per-4-rows softmax afterwards.
__global__ __launch_bounds__(1024) void out_kernel(
    const float* __restrict__ W2,    // (256, 256)
    const float* __restrict__ b2,    // (256)
    float* __restrict__ io)          // (131072, 256) h in, probs out
{
    const int tid = threadIdx.x;
    const int rg  = tid & 15;
    const int cg  = tid >> 4;        // 0..63
    const int m0  = blockIdx.x * 64;

    __shared__ float tile[64][260];

    // cooperative load of the h tile: 64 rows x 64 float4 slots = 4096 slots,
    // 1024 threads x 4 iters.
    #pragma unroll
    for (int i = 0; i < 4; ++i) {
        const int idx = tid + i*1024;     // 0..4095 float4 slots
        const int r   = idx >> 6;
        const int c4  = idx & 63;
        const f32x4 v = __builtin_nontemporal_load(
            (const f32x4*)(io + (size_t)(m0 + r)*256 + c4*4));
        *(f32x4*)&tile[r][c4*4] = v;
    }
    __syncthreads();

    float b2v[4];
    #pragma unroll
    for (int ci = 0; ci < 4; ++ci) b2v[ci] = b2[cg*4 + ci];

    float acc[4][4] = {};   // [ri][ci], row = rg + 16*ri, col = 4cg + ci

    #pragma unroll 4
    for (int k4 = 0; k4 < 64; ++k4) {
        const float4 h0 = *(const float4*)&tile[rg     ][k4*4];
        const float4 h1 = *(const float4*)&tile[rg + 16][k4*4];
        const float4 h2 = *(const float4*)&tile[rg + 32][k4*4];
        const float4 h3 = *(const float4*)&tile[rg + 48][k4*4];
        #pragma unroll
        for (int ci = 0; ci < 4; ++ci) {
            const float4 w = *(const float4*)(W2 + (size_t)(cg*4 + ci)*256 + k4*4);
            acc[0][ci] += dot4(w, h0);
            acc[1][ci] += dot4(w, h1);
            acc[2][ci] += dot4(w, h2);
            acc[3][ci] += dot4(w, h3);
        }
    }
    __syncthreads();   // all h reads done; tile reused for logits

    #pragma unroll
    for (int ri = 0; ri < 4; ++ri) {
        float4 v;
        v.x = acc[ri][0] + b2v[0];
        v.y = acc[ri][1] + b2v[1];
        v.z = acc[ri][2] + b2v[2];
        v.w = acc[ri][3] + b2v[3];
        *(float4*)&tile[rg + 16*ri][cg*4] = v;
    }
    __syncthreads();

    // softmax: wave w handles rows 4w..4w+3; lane l covers cols l+64s
    const int w = tid >> 6;          // 0..15
    const int l = tid & 63;
    #pragma unroll
    for (int rr = 0; rr < 4; ++rr) {
        const int r = w*4 + rr;
        const float v0 = tile[r][l      ];
        const float v1 = tile[r][l +  64];
        const float v2 = tile[r][l + 128];
        const float v3 = tile[r][l + 192];
        float m = fmaxf(fmaxf(v0, v1), fmaxf(v2, v3));
        #pragma unroll
        for (int off = 32; off > 0; off >>= 1)
            m = fmaxf(m, __shfl_xor(m, off));
        const float e0 = expf(v0 - m), e1 = expf(v1 - m);
        const float e2 = expf(v2 - m), e3 = expf(v3 - m);
        float s = e0 + e1 + e2 + e3;
        #pragma unroll
        for (int off = 32; off > 0; off >>= 1)
            s += __shfl_xor(s, off);
        const float inv = 1.0f / s;
        float* op = io + (size_t)(m0 + r)*256;
        __builtin_nontemporal_store(e0*inv, op + l      );
        __builtin_nontemporal_store(e1*inv, op + l +  64);
        __builtin_nontemporal_store(e2*inv, op + l + 128);
        __builtin_nontemporal_store(e3*inv, op + l + 192);
    }
}

extern "C" void kernel_launch(void* const* d_in, const int* in_sizes, int n_in,
                              void* d_out, int out_size, void* d_ws, size_t ws_size,
                              hipStream_t stream) {
    // inputs: input, encoder_output, W_ih, b_ih, W_hh, b_hh, W2, b2
    // (input and W_ih are mathematically unused: x_part = 0 @ W_ih.T + b_ih)
    const float* enc  = (const float*)d_in[1];
    const float* b_ih = (const float*)d_in[3];
    const float* W_hh = (const float*)d_in[4];
    const float* b_hh = (const float*)d_in[5];
    const float* W2   = (const float*)d_in[6];
    const float* b2   = (const float*)d_in[7];
    float* outp = (float*)d_out;

    hipLaunchKernelGGL(rec_kernel, dim3(128), dim3(1024), 0, stream,
                       enc, b_ih, W_hh, b_hh, outp);
    hipLaunchKernelGGL(out_kernel, dim3(2048), dim3(1024), 0, stream,
                       W2, b2, outp);
}

// Round 5
// 7141.767 us; speedup vs baseline: 2.2354x; 1.1062x over previous
//
#include <hip/hip_runtime.h>
#include <math.h>
#include <stdint.h>

typedef float f32x4 __attribute__((ext_vector_type(4)));

__device__ __forceinline__ float dot4(f32x4 a, f32x4 b) {
    return a.x*b.x + a.y*b.y + a.z*b.z + a.w*b.w;
}
__device__ __forceinline__ float sigm(float x) { return 1.0f/(1.0f+expf(-x)); }

// async 16B/lane global->LDS (lds dst = base + lane*16, wave-linear)
#define GLD16(g, l) __builtin_amdgcn_global_load_lds( \
    (const __attribute__((address_space(1))) uint32_t*)(g), \
    (__attribute__((address_space(3))) uint32_t*)(l), 16, 0, 0)

// ---------------- Kernel 1: LSTM recurrence, DMA-streamed W ----------------
// 128 blocks x 1024 threads (16 waves), 4 batch rows/block.
// W_hh (1 MiB) streamed per step through a 4-slot x 32KB LDS ring:
// 32 phases/step, 32 W-rows (1KB each) per phase. Wave w DMAs rows {2w,2w+1}
// of each phase and COMPUTES exactly those rows -> no cross-wave dep in the
// phase loop -> zero barriers there; per-wave s_waitcnt vmcnt(4) self-sync
// (phases p+1,p+2 = 4 issues stay in flight). 2 barriers/step (gates, h).
// Reference semantics: cell_state c0 CONSTANT (enc[:,-1,:]); carry = c_new.
__global__ __launch_bounds__(1024) void rec_kernel(
    const float* __restrict__ enc,   // (512, 64, 256)
    const float* __restrict__ b_ih,  // (1024)
    const float* __restrict__ W_hh,  // (1024, 256)
    const float* __restrict__ b_hh,  // (1024)
    float* __restrict__ hstage)      // (512, 256, 256) staging (= d_out)
{
    const int tid  = threadIdx.x;
    const int w    = tid >> 6;          // wave 0..15
    const int lane = tid & 63;
    const int kseg = lane & 15;         // 16-float K-window
    const int u    = (lane >> 4) & 1;   // which of the wave's 2 rows
    const int rh   = lane >> 5;         // batch-row half (rows 2rh, 2rh+1)
    const int b0   = blockIdx.x * 4;

    __shared__ float bufW[4][32*256];   // 4 ring slots x 32 rows x 1KB = 128KB
    __shared__ float gate_lds[4][1024]; // [batch r][gate-row]  16KB
    __shared__ float h_lds[4][256];     // 4KB   (total 148KB)

    // ---- pointwise identity (thread = (pj, pr)) ----
    const int pj = tid & 255, pr = tid >> 8;
    const float c0  = enc[(size_t)(b0+pr)*16384 + 16128 + pj];
    const float pb0 = b_ih[      pj] + b_hh[      pj];
    const float pb1 = b_ih[256 + pj] + b_hh[256 + pj];
    const float pb2 = b_ih[512 + pj] + b_hh[512 + pj];
    const float pb3 = b_ih[768 + pj] + b_hh[768 + pj];
    float* __restrict__ outp = hstage + (size_t)(b0+pr)*65536 + pj;

    // ---- compute-phase constants ----
    const int rr = 2*w + u;             // row-in-phase this thread reads
    // XOR bank swizzle (16B slots): stored slot x holds W slot
    // s = x ^ ((row&1)<<2) ^ ((x>>3)&3); read inverse below. Gives 4 words/bank
    // (b128 optimum) across the wave's 32 distinct addresses.
    int woff[4];                        // float offsets within a slot
    #pragma unroll
    for (int i = 0; i < 4; ++i) {
        int s = kseg*4 + i;
        int x = s ^ (u << 2) ^ ((s >> 3) & 3);
        woff[i] = rr*256 + x*4;
    }
    // DMA source slot permutation per lane for rows 2w (parity0), 2w+1 (parity1)
    const int sl0 = lane ^ ((lane >> 3) & 3);
    const int sl1 = lane ^ 4 ^ ((lane >> 3) & 3);

    #define ISSUE(pm, slot) {                                                  \
        const float* g0_ = W_hh + (size_t)((pm)*32 + 2*w    )*256 + sl0*4;     \
        const float* g1_ = W_hh + (size_t)((pm)*32 + 2*w + 1)*256 + sl1*4;     \
        GLD16(g0_, &bufW[slot][(2*w    )*256]);                                \
        GLD16(g1_, &bufW[slot][(2*w + 1)*256]); }

    f32x4 h0[4], h1[4];                 // this thread's h window, 2 batch rows
    #pragma unroll
    for (int i = 0; i < 4; ++i) { h0[i] = (f32x4)(0.f); h1[i] = (f32x4)(0.f); }

    // prologue: prime ring with phases 0,1,2
    ISSUE(0, 0); ISSUE(1, 1); ISSUE(2, 2);

    for (int t = 0; t < 256; ++t) {
        #pragma unroll 4
        for (int p = 0; p < 32; ++p) {
            // wait own phase-p issues done (p+1,p+2 = 4 stay in flight)
            asm volatile("s_waitcnt vmcnt(4)" ::: "memory");
            { const int pa = p + 3; ISSUE(pa & 31, pa & 3); }
            const float* wb = &bufW[p & 3][0];
            float a0 = 0.f, a1 = 0.f;
            #pragma unroll
            for (int i = 0; i < 4; ++i) {
                const f32x4 wv = *(const f32x4*)(wb + woff[i]);
                a0 += dot4(wv, h0[i]);
                a1 += dot4(wv, h1[i]);
            }
            // reduce over the 16 kseg lanes
            a0 += __shfl_xor(a0, 1); a1 += __shfl_xor(a1, 1);
            a0 += __shfl_xor(a0, 2); a1 += __shfl_xor(a1, 2);
            a0 += __shfl_xor(a0, 4); a1 += __shfl_xor(a1, 4);
            a0 += __shfl_xor(a0, 8); a1 += __shfl_xor(a1, 8);
            if (kseg == 0) {
                const int grow = p*32 + rr;
                gate_lds[rh*2    ][grow] = a0;
                gate_lds[rh*2 + 1][grow] = a1;
            }
        }
        asm volatile("s_waitcnt lgkmcnt(0)" ::: "memory");
        __builtin_amdgcn_s_barrier();           // (1) gates visible
        asm volatile("" ::: "memory");

        // ---- pointwise LSTM, thread (pj, pr) ----
        {
            const float g0 = gate_lds[pr][      pj] + pb0;
            const float g1 = gate_lds[pr][256 + pj] + pb1;
            const float g2 = gate_lds[pr][512 + pj] + pb2;
            const float g3 = gate_lds[pr][768 + pj] + pb3;
            const float cn = sigm(g1)*c0 + sigm(g0)*tanhf(g2);
            const float hn = sigm(g3)*tanhf(cn);
            h_lds[pr][pj] = cn;                 // carry h_{t+1} = c_new
            __builtin_nontemporal_store(hn, outp + t*256);
        }
        asm volatile("s_waitcnt lgkmcnt(0)" ::: "memory");
        __builtin_amdgcn_s_barrier();           // (2) h ready
        asm volatile("" ::: "memory");

        // reload h window into registers (broadcast reads)
        #pragma unroll
        for (int i = 0; i < 4; ++i) {
            h0[i] = *(const f32x4*)&h_lds[rh*2    ][kseg*16 + 4*i];
            h1[i] = *(const f32x4*)&h_lds[rh*2 + 1][kseg*16 + 4*i];
        }
    }
    #undef ISSUE
}

// ---------------- Kernel 2: logits + softmax, in place ----------------
// (unchanged from round 4 — verified correct)
__global__ __launch_bounds__(1024) void out_kernel(
    const float* __restrict__ W2,    // (256, 256)
    const float* __restrict__ b2,    // (256)
    float* __restrict__ io)          // (131072, 256) h in, probs out
{
    const int tid = threadIdx.x;
    const int rg  = tid & 15;
    const int cg  = tid >> 4;        // 0..63
    const int m0  = blockIdx.x * 64;

    __shared__ float tile[64][260];

    #pragma unroll
    for (int i = 0; i < 4; ++i) {
        const int idx = tid + i*1024;     // 0..4095 float4 slots
        const int r   = idx >> 6;
        const int c4  = idx & 63;
        const f32x4 v = __builtin_nontemporal_load(
            (const f32x4*)(io + (size_t)(m0 + r)*256 + c4*4));
        *(f32x4*)&tile[r][c4*4] = v;
    }
    __syncthreads();

    float b2v[4];
    #pragma unroll
    for (int ci = 0; ci < 4; ++ci) b2v[ci] = b2[cg*4 + ci];

    float acc[4][4] = {};

    #pragma unroll 4
    for (int k4 = 0; k4 < 64; ++k4) {
        const f32x4 h0 = *(const f32x4*)&tile[rg     ][k4*4];
        const f32x4 h1 = *(const f32x4*)&tile[rg + 16][k4*4];
        const f32x4 h2 = *(const f32x4*)&tile[rg + 32][k4*4];
        const f32x4 h3 = *(const f32x4*)&tile[rg + 48][k4*4];
        #pragma unroll
        for (int ci = 0; ci < 4; ++ci) {
            const f32x4 w = *(const f32x4*)(W2 + (size_t)(cg*4 + ci)*256 + k4*4);
            acc[0][ci] += dot4(w, h0);
            acc[1][ci] += dot4(w, h1);
            acc[2][ci] += dot4(w, h2);
            acc[3][ci] += dot4(w, h3);
        }
    }
    __syncthreads();

    #pragma unroll
    for (int ri = 0; ri < 4; ++ri) {
        f32x4 v;
        v.x = acc[ri][0] + b2v[0];
        v.y = acc[ri][1] + b2v[1];
        v.z = acc[ri][2] + b2v[2];
        v.w = acc[ri][3] + b2v[3];
        *(f32x4*)&tile[rg + 16*ri][cg*4] = v;
    }
    __syncthreads();

    const int wv_ = tid >> 6;
    const int l  = tid & 63;
    #pragma unroll
    for (int rr2 = 0; rr2 < 4; ++rr2) {
        const int r = wv_*4 + rr2;
        const float v0 = tile[r][l      ];
        const float v1 = tile[r][l +  64];
        const float v2 = tile[r][l + 128];
        const float v3 = tile[r][l + 192];
        float m = fmaxf(fmaxf(v0, v1), fmaxf(v2, v3));
        #pragma unroll
        for (int off = 32; off > 0; off >>= 1)
            m = fmaxf(m, __shfl_xor(m, off));
        const float e0 = expf(v0 - m), e1 = expf(v1 - m);
        const float e2 = expf(v2 - m), e3 = expf(v3 - m);
        float s = e0 + e1 + e2 + e3;
        #pragma unroll
        for (int off = 32; off > 0; off >>= 1)
            s += __shfl_xor(s, off);
        const float inv = 1.0f / s;
        float* op = io + (size_t)(m0 + r)*256;
        __builtin_nontemporal_store(e0*inv, op + l      );
        __builtin_nontemporal_store(e1*inv, op + l +  64);
        __builtin_nontemporal_store(e2*inv, op + l + 128);
        __builtin_nontemporal_store(e3*inv, op + l + 192);
    }
}

extern "C" void kernel_launch(void* const* d_in, const int* in_sizes, int n_in,
                              void* d_out, int out_size, void* d_ws, size_t ws_size,
                              hipStream_t stream) {
    // inputs: input, encoder_output, W_ih, b_ih, W_hh, b_hh, W2, b2
    // (input and W_ih are mathematically unused: x_part = 0 @ W_ih.T + b_ih)
    const float* enc  = (const float*)d_in[1];
    const float* b_ih = (const float*)d_in[3];
    const float* W_hh = (const float*)d_in[4];
    const float* b_hh = (const float*)d_in[5];
    const float* W2   = (const float*)d_in[6];
    const float* b2   = (const float*)d_in[7];
    float* outp = (float*)d_out;

    hipLaunchKernelGGL(rec_kernel, dim3(128), dim3(1024), 0, stream,
                       enc, b_ih, W_hh, b_hh, outp);
    hipLaunchKernelGGL(out_kernel, dim3(2048), dim3(1024), 0, stream,
                       W2, b2, outp);
}

// Round 6
// 4591.297 us; speedup vs baseline: 3.4771x; 1.5555x over previous
//
#include <hip/hip_runtime.h>
#include <math.h>
#include <stdint.h>

typedef float f32x4 __attribute__((ext_vector_type(4)));

__device__ __forceinline__ float sigm(float x) { return 1.0f/(1.0f+expf(-x)); }

// async 16B/lane global->LDS (lds dst = base + lane*16, wave-linear)
#define GLD16(g, l) __builtin_amdgcn_global_load_lds( \
    (const __attribute__((address_space(1))) uint32_t*)(g), \
    (__attribute__((address_space(3))) uint32_t*)(l), 16, 0, 0)

// sum across the 16-lane DPP row via row_ror rotations (pure VALU, no LDS)
__device__ __forceinline__ float red16(float v) {
    int t;
    t = __builtin_amdgcn_update_dpp(0, __float_as_int(v), 0x128, 0xf, 0xf, false);
    v += __int_as_float(t);   // ror 8
    t = __builtin_amdgcn_update_dpp(0, __float_as_int(v), 0x124, 0xf, 0xf, false);
    v += __int_as_float(t);   // ror 4
    t = __builtin_amdgcn_update_dpp(0, __float_as_int(v), 0x122, 0xf, 0xf, false);
    v += __int_as_float(t);   // ror 2
    t = __builtin_amdgcn_update_dpp(0, __float_as_int(v), 0x121, 0xf, 0xf, false);
    v += __int_as_float(t);   // ror 1
    return v;
}

// ---------------- Kernel 1: LSTM recurrence, DMA-streamed W ----------------
// 128 blocks x 512 threads (8 waves), 4 batch rows/block.
// W_hh (1 MiB) streamed per step through a 4-slot x 32KB LDS ring, 32 phases
// of 32 rows. Wave w DMAs AND computes rows {4w..4w+3} of each phase (no
// cross-wave dep -> no barriers in the phase loop; per-wave vmcnt self-sync).
// Lane (kseg=lane&15, r2=lane>>4): row 4w+r2, K-slots {kseg,kseg+16,+32,+48}
// (strided windows -> every ds_read_b128 is linear-equivalent, conflict-free,
// 1KB unique). h[4 batch][16 floats] lives in VGPRs; kseg-reduction via DPP
// row_ror on the VALU pipe (zero ds_swizzle). 2 barriers/step.
// Reference semantics: cell_state c0 CONSTANT (enc[:,-1,:]); carry = c_new.
__global__ __launch_bounds__(512) void rec_kernel(
    const float* __restrict__ enc,   // (512, 64, 256)
    const float* __restrict__ b_ih,  // (1024)
    const float* __restrict__ W_hh,  // (1024, 256)
    const float* __restrict__ b_hh,  // (1024)
    float* __restrict__ hstage)      // (512, 256, 256) staging (= d_out)
{
    const int tid  = threadIdx.x;
    const int w    = tid >> 6;          // wave 0..7
    const int lane = tid & 63;
    const int kseg = lane & 15;
    const int r2   = lane >> 4;         // 0..3
    const int b0   = blockIdx.x * 4;

    __shared__ float bufW[4][8192];     // 4 ring slots x 32 rows x 1KB = 128KB
    __shared__ float gate_lds[4][1024]; // [batch][gate-row] 16KB
    __shared__ float h_lds[4][256];     // 4KB  (total 148KB + pad)

    // ---- pointwise identity: thread (pj, ph) handles batches 2ph, 2ph+1 ----
    const int pj = tid & 255;
    const int ph = tid >> 8;            // 0..1
    const float c0A = enc[(size_t)(b0 + 2*ph    )*16384 + 16128 + pj];
    const float c0B = enc[(size_t)(b0 + 2*ph + 1)*16384 + 16128 + pj];
    const float pb0 = b_ih[      pj] + b_hh[      pj];
    const float pb1 = b_ih[256 + pj] + b_hh[256 + pj];
    const float pb2 = b_ih[512 + pj] + b_hh[512 + pj];
    const float pb3 = b_ih[768 + pj] + b_hh[768 + pj];
    float* __restrict__ outA = hstage + (size_t)(b0 + 2*ph)*65536 + pj;
    float* __restrict__ outB = outA + 65536;

    const int rloc = 4*w + r2;          // row-in-phase this lane computes

    #define ISSUE(pm, slot) do {                                               \
        const float* gsrc_ = W_hh + (size_t)((pm)*32 + 4*w)*256 + 4*lane;      \
        GLD16(gsrc_,        &bufW[slot][(4*w    )*256]);                       \
        GLD16(gsrc_ +  256, &bufW[slot][(4*w + 1)*256]);                       \
        GLD16(gsrc_ +  512, &bufW[slot][(4*w + 2)*256]);                       \
        GLD16(gsrc_ +  768, &bufW[slot][(4*w + 3)*256]);                       \
    } while (0)

    // h windows in registers: h[batch][chunk i] = h[b][(i*16+kseg)*4 ..+3]
    f32x4 h[4][4];
    #pragma unroll
    for (int b = 0; b < 4; ++b)
        #pragma unroll
        for (int i = 0; i < 4; ++i) h[b][i] = (f32x4)(0.0f);

    // prologue: prime ring with phases 0,1,2 (12 loads/wave in flight)
    ISSUE(0, 0); ISSUE(1, 1); ISSUE(2, 2);

    for (int t = 0; t < 256; ++t) {
        #pragma unroll 4
        for (int p = 0; p < 32; ++p) {
            // wait own phase-p DMAs done (8 younger stay in flight; stores
            // are youngest so vmcnt in-order retire keeps this safe)
            asm volatile("s_waitcnt vmcnt(8)" ::: "memory");
            { const int pa = p + 3; ISSUE(pa & 31, pa & 3); }  // W same every step -> wrap ok

            const float* wb = &bufW[p & 3][rloc*256 + kseg*4];
            f32x4 s0 = (f32x4)(0.f), s1 = (f32x4)(0.f);
            f32x4 s2 = (f32x4)(0.f), s3 = (f32x4)(0.f);
            #pragma unroll
            for (int i = 0; i < 4; ++i) {
                const f32x4 wv = *(const f32x4*)(wb + i*64);
                s0 += wv * h[0][i];
                s1 += wv * h[1][i];
                s2 += wv * h[2][i];
                s3 += wv * h[3][i];
            }
            float a0 = (s0.x + s0.y) + (s0.z + s0.w);
            float a1 = (s1.x + s1.y) + (s1.z + s1.w);
            float a2 = (s2.x + s2.y) + (s2.z + s2.w);
            float a3 = (s3.x + s3.y) + (s3.z + s3.w);
            a0 = red16(a0); a1 = red16(a1); a2 = red16(a2); a3 = red16(a3);
            if (kseg == 0) {
                const int grow = p*32 + rloc;
                gate_lds[0][grow] = a0;
                gate_lds[1][grow] = a1;
                gate_lds[2][grow] = a2;
                gate_lds[3][grow] = a3;
            }
        }
        asm volatile("s_waitcnt lgkmcnt(0)" ::: "memory");
        __builtin_amdgcn_s_barrier();           // (1) all gates visible

        // ---- pointwise LSTM for batches 2ph, 2ph+1, column pj ----
        {
            const float gA0 = gate_lds[2*ph    ][      pj] + pb0;
            const float gA1 = gate_lds[2*ph    ][256 + pj] + pb1;
            const float gA2 = gate_lds[2*ph    ][512 + pj] + pb2;
            const float gA3 = gate_lds[2*ph    ][768 + pj] + pb3;
            const float gB0 = gate_lds[2*ph + 1][      pj] + pb0;
            const float gB1 = gate_lds[2*ph + 1][256 + pj] + pb1;
            const float gB2 = gate_lds[2*ph + 1][512 + pj] + pb2;
            const float gB3 = gate_lds[2*ph + 1][768 + pj] + pb3;
            const float cnA = sigm(gA1)*c0A + sigm(gA0)*tanhf(gA2);
            const float cnB = sigm(gB1)*c0B + sigm(gB0)*tanhf(gB2);
            const float hnA = sigm(gA3)*tanhf(cnA);
            const float hnB = sigm(gB3)*tanhf(cnB);
            h_lds[2*ph    ][pj] = cnA;          // carry h_{t+1} = c_new
            h_lds[2*ph + 1][pj] = cnB;
            __builtin_nontemporal_store(hnA, outA + t*256);
            __builtin_nontemporal_store(hnB, outB + t*256);
        }
        asm volatile("s_waitcnt lgkmcnt(0)" ::: "memory");
        __builtin_amdgcn_s_barrier();           // (2) h ready

        // reload h windows (2-way bank aliasing = free; 16 instrs/wave)
        #pragma unroll
        for (int b = 0; b < 4; ++b)
            #pragma unroll
            for (int i = 0; i < 4; ++i)
                h[b][i] = *(const f32x4*)&h_lds[b][(i*16 + kseg)*4];
    }
    asm volatile("s_waitcnt vmcnt(0)" ::: "memory");  // drain DMA before endpgm
    #undef ISSUE
}

// ---------------- Kernel 2: logits + softmax, in place ----------------
// (unchanged — verified correct, ~1-2% of total time)
__global__ __launch_bounds__(1024) void out_kernel(
    const float* __restrict__ W2,    // (256, 256)
    const float* __restrict__ b2,    // (256)
    float* __restrict__ io)          // (131072, 256) h in, probs out
{
    const int tid = threadIdx.x;
    const int rg  = tid & 15;
    const int cg  = tid >> 4;        // 0..63
    const int m0  = blockIdx.x * 64;

    __shared__ float tile[64][260];

    #pragma unroll
    for (int i = 0; i < 4; ++i) {
        const int idx = tid + i*1024;     // 0..4095 float4 slots
        const int r   = idx >> 6;
        const int c4  = idx & 63;
        const f32x4 v = __builtin_nontemporal_load(
            (const f32x4*)(io + (size_t)(m0 + r)*256 + c4*4));
        *(f32x4*)&tile[r][c4*4] = v;
    }
    __syncthreads();

    float b2v[4];
    #pragma unroll
    for (int ci = 0; ci < 4; ++ci) b2v[ci] = b2[cg*4 + ci];

    float acc[4][4] = {};

    #pragma unroll 4
    for (int k4 = 0; k4 < 64; ++k4) {
        const f32x4 h0 = *(const f32x4*)&tile[rg     ][k4*4];
        const f32x4 h1 = *(const f32x4*)&tile[rg + 16][k4*4];
        const f32x4 h2 = *(const f32x4*)&tile[rg + 32][k4*4];
        const f32x4 h3 = *(const f32x4*)&tile[rg + 48][k4*4];
        #pragma unroll
        for (int ci = 0; ci < 4; ++ci) {
            const f32x4 wv = *(const f32x4*)(W2 + (size_t)(cg*4 + ci)*256 + k4*4);
            acc[0][ci] += wv.x*h0.x + wv.y*h0.y + wv.z*h0.z + wv.w*h0.w;
            acc[1][ci] += wv.x*h1.x + wv.y*h1.y + wv.z*h1.z + wv.w*h1.w;
            acc[2][ci] += wv.x*h2.x + wv.y*h2.y + wv.z*h2.z + wv.w*h2.w;
            acc[3][ci] += wv.x*h3.x + wv.y*h3.y + wv.z*h3.z + wv.w*h3.w;
        }
    }
    __syncthreads();

    #pragma unroll
    for (int ri = 0; ri < 4; ++ri) {
        f32x4 v;
        v.x = acc[ri][0] + b2v[0];
        v.y = acc[ri][1] + b2v[1];
        v.z = acc[ri][2] + b2v[2];
        v.w = acc[ri][3] + b2v[3];
        *(f32x4*)&tile[rg + 16*ri][cg*4] = v;
    }
    __syncthreads();

    const int wv_ = tid >> 6;
    const int l   = tid & 63;
    #pragma unroll
    for (int rr2 = 0; rr2 < 4; ++rr2) {
        const int r = wv_*4 + rr2;
        const float v0 = tile[r][l      ];
        const float v1 = tile[r][l +  64];
        const float v2 = tile[r][l + 128];
        const float v3 = tile[r][l + 192];
        float m = fmaxf(fmaxf(v0, v1), fmaxf(v2, v3));
        #pragma unroll
        for (int off = 32; off > 0; off >>= 1)
            m = fmaxf(m, __shfl_xor(m, off));
        const float e0 = expf(v0 - m), e1 = expf(v1 - m);
        const float e2 = expf(v2 - m), e3 = expf(v3 - m);
        float s = e0 + e1 + e2 + e3;
        #pragma unroll
        for (int off = 32; off > 0; off >>= 1)
            s += __shfl_xor(s, off);
        const float inv = 1.0f / s;
        float* op = io + (size_t)(m0 + r)*256;
        __builtin_nontemporal_store(e0*inv, op + l      );
        __builtin_nontemporal_store(e1*inv, op + l +  64);
        __builtin_nontemporal_store(e2*inv, op + l + 128);
        __builtin_nontemporal_store(e3*inv, op + l + 192);
    }
}

extern "C" void kernel_launch(void* const* d_in, const int* in_sizes, int n_in,
                              void* d_out, int out_size, void* d_ws, size_t ws_size,
                              hipStream_t stream) {
    // inputs: input, encoder_output, W_ih, b_ih, W_hh, b_hh, W2, b2
    // (input and W_ih are mathematically unused: x_part = 0 @ W_ih.T + b_ih)
    const float* enc  = (const float*)d_in[1];
    const float* b_ih = (const float*)d_in[3];
    const float* W_hh = (const float*)d_in[4];
    const float* b_hh = (const float*)d_in[5];
    const float* W2   = (const float*)d_in[6];
    const float* b2   = (const float*)d_in[7];
    float* outp = (float*)d_out;

    hipLaunchKernelGGL(rec_kernel, dim3(128), dim3(512), 0, stream,
                       enc, b_ih, W_hh, b_hh, outp);
    hipLaunchKernelGGL(out_kernel, dim3(2048), dim3(1024), 0, stream,
                       W2, b2, outp);
}